// Round 1
// 299.859 us; speedup vs baseline: 1.0686x; 1.0686x over previous
//
#include <hip/hip_runtime.h>
#include <math.h>

#define BATCH 8
#define CDIM 256
#define NDIM 2048
#define SCALE 0.0625f  // 1/sqrt(256)

typedef _Float16 half8v __attribute__((ext_vector_type(8)));
typedef _Float16 half4v __attribute__((ext_vector_type(4)));
typedef float floatx4 __attribute__((ext_vector_type(4)));

// workspace offsets (bytes)
#define WS_SPART 0                              // 8*16*2048 floats = 1 MB
#define WS_KT    1048576
#define WS_QT    (1048576 + 8388608)
#define WS_EHT   (1048576 + 2 * 8388608)
// total ws use: ~81 MB

// Bs chunk swizzle: per-row rotation, conflict-free for staging-store,
// MFMA fragment reads, and the W transpose gather (bank math verified).
#define BSWZ(c, j) (((((c) + (j) + ((j) >> 3)) & 7)) << 3)

// ---------------------------------------------------------------------------
// prep: K,Q -> fp16 transposed+tiled [b][ib(16)][cb(8)][i(128)][c(32)]
// ---------------------------------------------------------------------------
__global__ __launch_bounds__(256) void prep_kernel(const float* __restrict__ Q,
                                                   const float* __restrict__ K,
                                                   _Float16* __restrict__ Kt,
                                                   _Float16* __restrict__ Qt) {
    const int g = blockIdx.x * 256 + threadIdx.x;
    const float* src = (blockIdx.y == 0) ? K : Q;
    _Float16* dst = (blockIdx.y == 0) ? Kt : Qt;
    const int b = g >> 15, r = g & 32767;
    const int iq = r & 511, cq = r >> 9;  // i-quad (512), c-quad (64)
    const float* p = src + (size_t)b * CDIM * NDIM + (size_t)(cq * 4) * NDIM + iq * 4;
    float fr[4][4];
    *(float4*)fr[0] = *(const float4*)(p);
    *(float4*)fr[1] = *(const float4*)(p + NDIM);
    *(float4*)fr[2] = *(const float4*)(p + 2 * NDIM);
    *(float4*)fr[3] = *(const float4*)(p + 3 * NDIM);
    const int cb = cq >> 3, cc0 = (cq & 7) * 4;
#pragma unroll
    for (int ii = 0; ii < 4; ++ii) {
        const int i = iq * 4 + ii;
        const int ib = i >> 7, il = i & 127;
        half4v h = {(_Float16)fr[0][ii], (_Float16)fr[1][ii],
                    (_Float16)fr[2][ii], (_Float16)fr[3][ii]};
        *(half4v*)&dst[((((size_t)(b * 16 + ib) * 8 + cb) * 128 + il) * 32) + cc0] = h;
    }
}

// ---------------------------------------------------------------------------
// GEMM1: E = exp(SCALE * K^T Q). Main loop identical (proven). Epilogue:
// exp -> fp16 -> LDS 128x128 chunk-swizzled transpose -> coalesced half8
// stores to EhT[b][jb(32)][ib(32)][jl(64)][il(64)].
// NEW: per-block column partial sums harvested from the fp32 exp values in
// registers -> Spart[b][ib2][j] (replaces the colsum kernel).
// ---------------------------------------------------------------------------
__global__ __launch_bounds__(256) void gemm1_kernel(const _Float16* __restrict__ Kt,
                                                    const _Float16* __restrict__ Qt,
                                                    _Float16* __restrict__ EhT,
                                                    float* __restrict__ Spart) {
    __shared__ _Float16 Al[128 * 40];
    __shared__ _Float16 Bl[128 * 40];
    __shared__ _Float16 LT[128 * 128];
    __shared__ float Sl[2][128];
    const int b = blockIdx.z, ib2 = blockIdx.y, jb2 = blockIdx.x;
    const _Float16* Ab = Kt + (size_t)(b * 16 + ib2) * 8 * 4096;
    const _Float16* Bb = Qt + (size_t)(b * 16 + jb2) * 8 * 4096;
    const int t = threadIdx.x, wave = t >> 6, lane = t & 63;
    const int wy = wave >> 1, wx = wave & 1, quad = lane >> 4, lr = lane & 15;
    floatx4 acc[4][4] = {};
    const int ci0 = t * 2, ci1 = t * 2 + 1;
    _Float16* wA0 = &Al[(ci0 >> 2) * 40 + (ci0 & 3) * 8];
    _Float16* wA1 = &Al[(ci1 >> 2) * 40 + (ci1 & 3) * 8];
    _Float16* wB0 = &Bl[(ci0 >> 2) * 40 + (ci0 & 3) * 8];
    _Float16* wB1 = &Bl[(ci1 >> 2) * 40 + (ci1 & 3) * 8];

    for (int cb = 0; cb < 8; ++cb) {
        half8v a0 = *(const half8v*)(Ab + cb * 4096 + ci0 * 8);
        half8v a1 = *(const half8v*)(Ab + cb * 4096 + ci1 * 8);
        half8v b0 = *(const half8v*)(Bb + cb * 4096 + ci0 * 8);
        half8v b1 = *(const half8v*)(Bb + cb * 4096 + ci1 * 8);
        __syncthreads();
        *(half8v*)wA0 = a0; *(half8v*)wA1 = a1;
        *(half8v*)wB0 = b0; *(half8v*)wB1 = b1;
        __syncthreads();
        half8v af[4], bf[4];
#pragma unroll
        for (int m = 0; m < 4; ++m)
            af[m] = *(const half8v*)&Al[(wy * 64 + m * 16 + lr) * 40 + quad * 8];
#pragma unroll
        for (int n = 0; n < 4; ++n)
            bf[n] = *(const half8v*)&Bl[(wx * 64 + n * 16 + lr) * 40 + quad * 8];
#pragma unroll
        for (int m = 0; m < 4; ++m)
#pragma unroll
            for (int n = 0; n < 4; ++n)
                acc[m][n] = __builtin_amdgcn_mfma_f32_16x16x32_f16(af[m], bf[n], acc[m][n], 0, 0, 0);
    }

    // epilogue: exp -> LDS transpose (chunk-swizzled) + column partial sums
    float psum[4] = {0.f, 0.f, 0.f, 0.f};
#pragma unroll
    for (int m = 0; m < 4; ++m) {
#pragma unroll
        for (int n = 0; n < 4; ++n) {
            const int j_loc = wx * 64 + n * 16 + lr;
#pragma unroll
            for (int r = 0; r < 4; ++r) {
                const int i_loc = wy * 64 + m * 16 + quad * 4 + r;
                float e = __expf(acc[m][n][r] * SCALE);
                psum[n] += e;
                LT[j_loc * 128 + (((i_loc >> 3) ^ (j_loc & 7)) << 3) + (i_loc & 7)] = (_Float16)e;
            }
        }
    }
    // quad-butterfly: sum over this wave's 64 i rows for each of its 64 j's
#pragma unroll
    for (int n = 0; n < 4; ++n) {
        float s = psum[n];
        s += __shfl_xor(s, 16, 64);
        s += __shfl_xor(s, 32, 64);
        if (quad == 0) Sl[wy][wx * 64 + n * 16 + lr] = s;
    }
    __syncthreads();
    if (t < 128)
        Spart[((size_t)(b * 16 + ib2)) * 2048 + jb2 * 128 + t] = Sl[0][t] + Sl[1][t];

    const int jh = wave >> 1, ih = wave & 1;
    _Float16* dst = EhT + ((size_t)((b * 32 + jb2 * 2 + jh) * 32) + ib2 * 2 + ih) * 4096;
#pragma unroll
    for (int cc = 0; cc < 8; ++cc) {
        const int j = jh * 64 + cc * 8 + (lane >> 3);
        half8v h = *(const half8v*)&LT[j * 128 + (((ih * 8 + (lane & 7)) ^ (lane >> 3)) << 3)];
        *(half8v*)&dst[cc * 512 + lane * 8] = h;
    }
}

// ---------------------------------------------------------------------------
// GEMM2 (fused): out[b,c,j] = invS[j] * sum_i V[c,i] * E[i,j]  AND
// W[b,i,j] = E[i,j] * invS[j] written straight from the staged B tiles.
// Block 128c x 128j, full K per block, grid 16x2x8 = 256.
// Prologue folds the 16 Spart partials -> invSl (replaces colsum+invS).
// Bs rows carry the BSWZ chunk rotation so the MFMA fragment reads AND the
// W transpose gather are both bank-conflict-clean. The two cc2 blocks of a
// j-strip alternate W-duty by iteration parity (even split, full coverage).
// ---------------------------------------------------------------------------
__global__ __launch_bounds__(256) void gemm2_kernel(const float* __restrict__ V,
                                                    const _Float16* __restrict__ EhT,
                                                    const float* __restrict__ Spart,
                                                    float* __restrict__ W,
                                                    float* __restrict__ Out) {
    __shared__ _Float16 As[128 * 72];
    __shared__ _Float16 Bs[128 * 72];
    __shared__ float invSl[128];
    const int b = blockIdx.z, cc2 = blockIdx.y, jb2 = blockIdx.x;
    const int t = threadIdx.x, wave = t >> 6, lane = t & 63;
    const int wy = wave >> 1, wx = wave & 1, quad = lane >> 4, lr = lane & 15;
    const float* Vb = V + ((size_t)(b * 256 + cc2 * 128)) * 2048;
    floatx4 acc[4][4] = {};

    if (t < 128) {
        float s = 0.f;
#pragma unroll
        for (int p = 0; p < 16; ++p)
            s += Spart[((size_t)(b * 16 + p)) * 2048 + jb2 * 128 + t];
        invSl[t] = 1.0f / s;
    }
    __syncthreads();

    // W-path thread mapping: 4 consecutive j x 8 consecutive i per thread
    const int tj4 = t & 31, ti8 = t >> 5, j0 = tj4 * 4;
    const float4 ivW = make_float4(invSl[j0], invSl[j0 + 1], invSl[j0 + 2], invSl[j0 + 3]);
    float* Wb = W + ((size_t)b * 2048) * 2048 + jb2 * 128;

    for (int it = 0; it < 32; ++it) {
        float4 av[8];
#pragma unroll
        for (int u = 0; u < 8; ++u) {
            const int f = u * 256 + t;
            const int c = f >> 4, i4 = f & 15;
            av[u] = *(const float4*)&Vb[(size_t)c * 2048 + it * 64 + i4 * 4];
        }
        half8v bv[4];
#pragma unroll
        for (int u = 0; u < 4; ++u) {
            const int f = u * 256 + t;  // 0..1023
            const int jl = f >> 3, c8 = f & 7;
            const int jb = jb2 * 2 + (jl >> 6);
            bv[u] = *(const half8v*)&EhT[((size_t)((b * 32 + jb) * 32) + it) * 4096 +
                                         (jl & 63) * 64 + c8 * 8];
        }
        __syncthreads();
#pragma unroll
        for (int u = 0; u < 8; ++u) {
            const int f = u * 256 + t;
            const int c = f >> 4, i4 = f & 15;
            half4v h = {(_Float16)av[u].x, (_Float16)av[u].y,
                        (_Float16)av[u].z, (_Float16)av[u].w};
            *(half4v*)&As[c * 72 + i4 * 4] = h;
        }
#pragma unroll
        for (int u = 0; u < 4; ++u) {
            const int f = u * 256 + t;
            const int jl = f >> 3, c8 = f & 7;
            *(half8v*)&Bs[jl * 72 + BSWZ(c8, jl)] = bv[u];
        }
        __syncthreads();
#pragma unroll
        for (int ks = 0; ks < 2; ++ks) {
            half8v af[4], bf[4];
#pragma unroll
            for (int m = 0; m < 4; ++m)
                af[m] = *(const half8v*)&As[(wy * 64 + m * 16 + lr) * 72 + ks * 32 + quad * 8];
#pragma unroll
            for (int n = 0; n < 4; ++n) {
                const int row = wx * 64 + n * 16 + lr;
                bf[n] = *(const half8v*)&Bs[row * 72 + BSWZ(ks * 4 + quad, row)];
            }
#pragma unroll
            for (int m = 0; m < 4; ++m)
#pragma unroll
                for (int n = 0; n < 4; ++n)
                    acc[m][n] = __builtin_amdgcn_mfma_f32_16x16x32_f16(af[m], bf[n], acc[m][n], 0, 0, 0);
        }
        // fused W write: this block handles alternating iterations (even/odd
        // split with its cc2 sibling). Bs stays valid until next iter's sync.
        if ((it & 1) == cc2) {
            half8v hvr[4];
#pragma unroll
            for (int r = 0; r < 4; ++r) {
                const int j = j0 + r;
                hvr[r] = *(const half8v*)&Bs[j * 72 + BSWZ(ti8, j)];
            }
            float* Wr = Wb + (size_t)(it * 64 + ti8 * 8) * 2048;
#pragma unroll
            for (int e = 0; e < 8; ++e) {
                float4 o = make_float4((float)hvr[0][e] * ivW.x,
                                       (float)hvr[1][e] * ivW.y,
                                       (float)hvr[2][e] * ivW.z,
                                       (float)hvr[3][e] * ivW.w);
                *(float4*)&Wr[(size_t)e * 2048 + j0] = o;
            }
        }
    }

    float* Ob = Out + ((size_t)(b * 256 + cc2 * 128)) * 2048 + jb2 * 128;
    float iv[4];
#pragma unroll
    for (int n = 0; n < 4; ++n)
        iv[n] = invSl[wx * 64 + n * 16 + lr];
#pragma unroll
    for (int m = 0; m < 4; ++m) {
        const int c0r = wy * 64 + m * 16 + quad * 4;
#pragma unroll
        for (int n = 0; n < 4; ++n) {
            const int j = wx * 64 + n * 16 + lr;
#pragma unroll
            for (int r = 0; r < 4; ++r)
                Ob[(size_t)(c0r + r) * 2048 + j] = acc[m][n][r] * iv[n];
        }
    }
}

extern "C" void kernel_launch(void* const* d_in, const int* in_sizes, int n_in,
                              void* d_out, int out_size, void* d_ws, size_t ws_size,
                              hipStream_t stream) {
    const float* q = (const float*)d_in[0];
    const float* k = (const float*)d_in[1];
    const float* v = (const float*)d_in[2];
    float* out = (float*)d_out;
    float* w = out + (size_t)BATCH * CDIM * NDIM;  // weights region

    char* ws = (char*)d_ws;
    float* Spart = (float*)(ws + WS_SPART);
    _Float16* Kt = (_Float16*)(ws + WS_KT);
    _Float16* Qt = (_Float16*)(ws + WS_QT);
    _Float16* EhT = (_Float16*)(ws + WS_EHT);

    prep_kernel<<<dim3(1024, 2), 256, 0, stream>>>(q, k, Kt, Qt);
    gemm1_kernel<<<dim3(16, 16, 8), 256, 0, stream>>>(Kt, Qt, EhT, Spart);
    gemm2_kernel<<<dim3(16, 2, 8), 256, 0, stream>>>(v, EhT, Spart, w, out);
}

// Round 2
// 274.138 us; speedup vs baseline: 1.1688x; 1.0938x over previous
//
#include <hip/hip_runtime.h>
#include <math.h>

#define BATCH 8
#define CDIM 256
#define NDIM 2048
#define SCALE 0.0625f  // 1/sqrt(256)

typedef _Float16 half8v __attribute__((ext_vector_type(8)));
typedef _Float16 half4v __attribute__((ext_vector_type(4)));
typedef float floatx4 __attribute__((ext_vector_type(4)));

// workspace offsets (bytes)
#define WS_SPART 0                      // 8*16*2048 floats = 1 MB
#define WS_KT    1048576                // 8.4 MB
#define WS_QT    9437184                // 8.4 MB
#define WS_VT    17825792               // 8.4 MB (fp16 V, plain [b][c][i])
#define WS_EHT   26214400               // 67 MB
// total ws use: ~89 MB

// Bs/As chunk swizzle: per-row rotation, conflict-free for staging-store,
// MFMA fragment reads, and the W transpose gather.
#define BSWZ(c, j) (((((c) + (j) + ((j) >> 3)) & 7)) << 3)

// ---------------------------------------------------------------------------
// prep: K,Q -> fp16 transposed+tiled [b][ib(16)][cb(8)][i(128)][c(32)];
// V -> fp16 cast, layout unchanged [b][c][i].
// ---------------------------------------------------------------------------
__global__ __launch_bounds__(256) void prep_kernel(const float* __restrict__ Q,
                                                   const float* __restrict__ K,
                                                   const float* __restrict__ V,
                                                   _Float16* __restrict__ Kt,
                                                   _Float16* __restrict__ Qt,
                                                   _Float16* __restrict__ Vt) {
    if (blockIdx.y == 2) {
        const int t = threadIdx.x;
#pragma unroll
        for (int u = 0; u < 4; ++u) {
            const size_t idx = (size_t)blockIdx.x * 4096 + (u * 256 + t) * 4;
            float4 f = *(const float4*)&V[idx];
            half4v h = {(_Float16)f.x, (_Float16)f.y, (_Float16)f.z, (_Float16)f.w};
            *(half4v*)&Vt[idx] = h;
        }
        return;
    }
    const int g = blockIdx.x * 256 + threadIdx.x;
    const float* src = (blockIdx.y == 0) ? K : Q;
    _Float16* dst = (blockIdx.y == 0) ? Kt : Qt;
    const int b = g >> 15, r = g & 32767;
    const int iq = r & 511, cq = r >> 9;  // i-quad (512), c-quad (64)
    const float* p = src + (size_t)b * CDIM * NDIM + (size_t)(cq * 4) * NDIM + iq * 4;
    float fr[4][4];
    *(float4*)fr[0] = *(const float4*)(p);
    *(float4*)fr[1] = *(const float4*)(p + NDIM);
    *(float4*)fr[2] = *(const float4*)(p + 2 * NDIM);
    *(float4*)fr[3] = *(const float4*)(p + 3 * NDIM);
    const int cb = cq >> 3, cc0 = (cq & 7) * 4;
#pragma unroll
    for (int ii = 0; ii < 4; ++ii) {
        const int i = iq * 4 + ii;
        const int ib = i >> 7, il = i & 127;
        half4v h = {(_Float16)fr[0][ii], (_Float16)fr[1][ii],
                    (_Float16)fr[2][ii], (_Float16)fr[3][ii]};
        *(half4v*)&dst[((((size_t)(b * 16 + ib) * 8 + cb) * 128 + il) * 32) + cc0] = h;
    }
}

// ---------------------------------------------------------------------------
// GEMM1: E = exp(SCALE * K^T Q). Main loop identical (proven). Epilogue:
// exp -> fp16 -> LDS 128x128 chunk-swizzled transpose -> coalesced half8
// stores to EhT[b][jb(32)][ib(32)][jl(64)][il(64)] + per-block column
// partial sums -> Spart[b][ib2][j].
// ---------------------------------------------------------------------------
__global__ __launch_bounds__(256) void gemm1_kernel(const _Float16* __restrict__ Kt,
                                                    const _Float16* __restrict__ Qt,
                                                    _Float16* __restrict__ EhT,
                                                    float* __restrict__ Spart) {
    __shared__ _Float16 Al[128 * 40];
    __shared__ _Float16 Bl[128 * 40];
    __shared__ _Float16 LT[128 * 128];
    __shared__ float Sl[2][128];
    const int b = blockIdx.z, ib2 = blockIdx.y, jb2 = blockIdx.x;
    const _Float16* Ab = Kt + (size_t)(b * 16 + ib2) * 8 * 4096;
    const _Float16* Bb = Qt + (size_t)(b * 16 + jb2) * 8 * 4096;
    const int t = threadIdx.x, wave = t >> 6, lane = t & 63;
    const int wy = wave >> 1, wx = wave & 1, quad = lane >> 4, lr = lane & 15;
    floatx4 acc[4][4] = {};
    const int ci0 = t * 2, ci1 = t * 2 + 1;
    _Float16* wA0 = &Al[(ci0 >> 2) * 40 + (ci0 & 3) * 8];
    _Float16* wA1 = &Al[(ci1 >> 2) * 40 + (ci1 & 3) * 8];
    _Float16* wB0 = &Bl[(ci0 >> 2) * 40 + (ci0 & 3) * 8];
    _Float16* wB1 = &Bl[(ci1 >> 2) * 40 + (ci1 & 3) * 8];

    for (int cb = 0; cb < 8; ++cb) {
        half8v a0 = *(const half8v*)(Ab + cb * 4096 + ci0 * 8);
        half8v a1 = *(const half8v*)(Ab + cb * 4096 + ci1 * 8);
        half8v b0 = *(const half8v*)(Bb + cb * 4096 + ci0 * 8);
        half8v b1 = *(const half8v*)(Bb + cb * 4096 + ci1 * 8);
        __syncthreads();
        *(half8v*)wA0 = a0; *(half8v*)wA1 = a1;
        *(half8v*)wB0 = b0; *(half8v*)wB1 = b1;
        __syncthreads();
        half8v af[4], bf[4];
#pragma unroll
        for (int m = 0; m < 4; ++m)
            af[m] = *(const half8v*)&Al[(wy * 64 + m * 16 + lr) * 40 + quad * 8];
#pragma unroll
        for (int n = 0; n < 4; ++n)
            bf[n] = *(const half8v*)&Bl[(wx * 64 + n * 16 + lr) * 40 + quad * 8];
#pragma unroll
        for (int m = 0; m < 4; ++m)
#pragma unroll
            for (int n = 0; n < 4; ++n)
                acc[m][n] = __builtin_amdgcn_mfma_f32_16x16x32_f16(af[m], bf[n], acc[m][n], 0, 0, 0);
    }

    // epilogue: exp -> LDS transpose (chunk-swizzled) + column partial sums
    float psum[4] = {0.f, 0.f, 0.f, 0.f};
#pragma unroll
    for (int m = 0; m < 4; ++m) {
#pragma unroll
        for (int n = 0; n < 4; ++n) {
            const int j_loc = wx * 64 + n * 16 + lr;
#pragma unroll
            for (int r = 0; r < 4; ++r) {
                const int i_loc = wy * 64 + m * 16 + quad * 4 + r;
                float e = __expf(acc[m][n][r] * SCALE);
                psum[n] += e;
                LT[j_loc * 128 + (((i_loc >> 3) ^ (j_loc & 7)) << 3) + (i_loc & 7)] = (_Float16)e;
            }
        }
    }
#pragma unroll
    for (int n = 0; n < 4; ++n) {
        float s = psum[n];
        s += __shfl_xor(s, 16, 64);
        s += __shfl_xor(s, 32, 64);
        if (quad == 0) Sl[wy][wx * 64 + n * 16 + lr] = s;
    }
    __syncthreads();
    if (t < 128)
        Spart[((size_t)(b * 16 + ib2)) * 2048 + jb2 * 128 + t] = Sl[0][t] + Sl[1][t];

    const int jh = wave >> 1, ih = wave & 1;
    _Float16* dst = EhT + ((size_t)((b * 32 + jb2 * 2 + jh) * 32) + ib2 * 2 + ih) * 4096;
#pragma unroll
    for (int cc = 0; cc < 8; ++cc) {
        const int j = jh * 64 + cc * 8 + (lane >> 3);
        half8v h = *(const half8v*)&LT[j * 128 + (((ih * 8 + (lane & 7)) ^ (lane >> 3)) << 3)];
        *(half8v*)&dst[cc * 512 + lane * 8] = h;
    }
}

// ---------------------------------------------------------------------------
// GEMM2 (fused): out[b,c,j] = invS[j] * sum_i V[c,i] * E[i,j]  AND
// W[b,i,j] = E[i,j] * invS[j] written from the staged B tiles.
// Block 128c x 128j, 512 threads (8 waves: 2c x 4j), full K per block,
// grid 16x2x8 = 256 (1 block/CU, cc2 siblings share an XCD -> L2 reuse).
// Register prefetch pipeline: next iter's V/EhT loads issued after the
// staging barrier, consumed at the next staging -> latency hides under MFMA.
// ---------------------------------------------------------------------------
#define G2_LOAD(IT, AV, BV)                                                        \
    do {                                                                           \
        _Pragma("unroll") for (int u = 0; u < 2; ++u) {                            \
            const int f = u * 512 + t;                                             \
            const int c = f >> 3, i8 = f & 7;                                      \
            AV[u] = *(const half8v*)&Vtb[(size_t)c * 2048 + (IT) * 64 + i8 * 8];   \
        }                                                                          \
        _Pragma("unroll") for (int u = 0; u < 2; ++u) {                            \
            const int f = u * 512 + t;                                             \
            const int jl = f >> 3, c8 = f & 7;                                     \
            const int jbv = jb2 * 2 + (jl >> 6);                                   \
            BV[u] = *(const half8v*)&EhT[((size_t)((b * 32 + jbv) * 32) + (IT)) *  \
                                             4096 +                                \
                                         (jl & 63) * 64 + c8 * 8];                 \
        }                                                                          \
    } while (0)

#define G2_STEP(IT, AVc, BVc, ITN, AVn, BVn, DUTY)                                 \
    do {                                                                           \
        __syncthreads();                                                           \
        _Pragma("unroll") for (int u = 0; u < 2; ++u) {                            \
            const int f = u * 512 + t;                                             \
            const int c = f >> 3, i8 = f & 7;                                      \
            *(half8v*)&As[c * 72 + BSWZ(i8, c)] = AVc[u];                          \
        }                                                                          \
        _Pragma("unroll") for (int u = 0; u < 2; ++u) {                            \
            const int f = u * 512 + t;                                             \
            const int jl = f >> 3, c8 = f & 7;                                     \
            *(half8v*)&Bs[jl * 72 + BSWZ(c8, jl)] = BVc[u];                        \
        }                                                                          \
        __syncthreads();                                                           \
        G2_LOAD(ITN, AVn, BVn);                                                    \
        _Pragma("unroll") for (int ks = 0; ks < 2; ++ks) {                         \
            half8v af[4], bf[2];                                                   \
            _Pragma("unroll") for (int m = 0; m < 4; ++m) {                        \
                const int row = wy * 64 + m * 16 + lr;                             \
                af[m] = *(const half8v*)&As[row * 72 + BSWZ(ks * 4 + quad, row)];  \
            }                                                                      \
            _Pragma("unroll") for (int n = 0; n < 2; ++n) {                        \
                const int row = wx * 32 + n * 16 + lr;                             \
                bf[n] = *(const half8v*)&Bs[row * 72 + BSWZ(ks * 4 + quad, row)];  \
            }                                                                      \
            _Pragma("unroll") for (int m = 0; m < 4; ++m)                          \
                _Pragma("unroll") for (int n = 0; n < 2; ++n)                      \
                    acc[m][n] = __builtin_amdgcn_mfma_f32_16x16x32_f16(            \
                        af[m], bf[n], acc[m][n], 0, 0, 0);                         \
        }                                                                          \
        if (DUTY) {                                                                \
            half8v hv0 = *(const half8v*)&Bs[j0 * 72 + BSWZ(ti, j0)];              \
            half8v hv1 = *(const half8v*)&Bs[(j0 + 1) * 72 + BSWZ(ti, j0 + 1)];    \
            float* Wr = Wb + (size_t)((IT) * 64 + ti * 8) * 2048;                  \
            _Pragma("unroll") for (int e = 0; e < 8; ++e) {                        \
                float2 o = make_float2((float)hv0[e] * iv0, (float)hv1[e] * iv1);  \
                *(float2*)&Wr[(size_t)e * 2048 + j0] = o;                          \
            }                                                                      \
        }                                                                          \
    } while (0)

__global__ __launch_bounds__(512) void gemm2_kernel(const _Float16* __restrict__ Vt,
                                                    const _Float16* __restrict__ EhT,
                                                    const float* __restrict__ Spart,
                                                    float* __restrict__ W,
                                                    float* __restrict__ Out) {
    __shared__ _Float16 As[128 * 72];
    __shared__ _Float16 Bs[128 * 72];
    __shared__ float invSl[128];
    const int b = blockIdx.z, cc2 = blockIdx.y, jb2 = blockIdx.x;
    const int t = threadIdx.x, wave = t >> 6, lane = t & 63;
    const int wy = wave >> 2, wx = wave & 3, quad = lane >> 4, lr = lane & 15;
    const _Float16* Vtb = Vt + ((size_t)(b * 256 + cc2 * 128)) * 2048;
    floatx4 acc[4][2] = {};

    if (t < 128) {
        float s = 0.f;
#pragma unroll
        for (int p = 0; p < 16; ++p)
            s += Spart[((size_t)(b * 16 + p)) * 2048 + jb2 * 128 + t];
        invSl[t] = 1.0f / s;
    }
    __syncthreads();

    // W-path thread mapping: 2 consecutive j x 8 consecutive i per thread
    const int j0 = (t & 63) * 2, ti = t >> 6;
    const float iv0 = invSl[j0], iv1 = invSl[j0 + 1];
    float* Wb = W + ((size_t)b * 2048) * 2048 + jb2 * 128;

    half8v av0[2], bv0[2], av1[2], bv1[2];
    G2_LOAD(0, av0, bv0);
    const bool dutyE = (cc2 == 0), dutyO = (cc2 == 1);
    for (int ip = 0; ip < 16; ++ip) {
        const int itE = ip * 2, itO = ip * 2 + 1;
        G2_STEP(itE, av0, bv0, itO, av1, bv1, dutyE);
        G2_STEP(itO, av1, bv1, (itO + 1) & 31, av0, bv0, dutyO);
    }

    float* Ob = Out + ((size_t)(b * 256 + cc2 * 128)) * 2048 + jb2 * 128;
    float iv[2];
#pragma unroll
    for (int n = 0; n < 2; ++n)
        iv[n] = invSl[wx * 32 + n * 16 + lr];
#pragma unroll
    for (int m = 0; m < 4; ++m) {
        const int c0r = wy * 64 + m * 16 + quad * 4;
#pragma unroll
        for (int n = 0; n < 2; ++n) {
            const int j = wx * 32 + n * 16 + lr;
#pragma unroll
            for (int r = 0; r < 4; ++r)
                Ob[(size_t)(c0r + r) * 2048 + j] = acc[m][n][r] * iv[n];
        }
    }
}

extern "C" void kernel_launch(void* const* d_in, const int* in_sizes, int n_in,
                              void* d_out, int out_size, void* d_ws, size_t ws_size,
                              hipStream_t stream) {
    const float* q = (const float*)d_in[0];
    const float* k = (const float*)d_in[1];
    const float* v = (const float*)d_in[2];
    float* out = (float*)d_out;
    float* w = out + (size_t)BATCH * CDIM * NDIM;  // weights region

    char* ws = (char*)d_ws;
    float* Spart = (float*)(ws + WS_SPART);
    _Float16* Kt = (_Float16*)(ws + WS_KT);
    _Float16* Qt = (_Float16*)(ws + WS_QT);
    _Float16* Vt = (_Float16*)(ws + WS_VT);
    _Float16* EhT = (_Float16*)(ws + WS_EHT);

    prep_kernel<<<dim3(1024, 3), 256, 0, stream>>>(q, k, v, Kt, Qt, Vt);
    gemm1_kernel<<<dim3(16, 16, 8), 256, 0, stream>>>(Kt, Qt, EhT, Spart);
    gemm2_kernel<<<dim3(16, 2, 8), 512, 0, stream>>>(Vt, EhT, Spart, w, out);
}

// Round 3
// 268.626 us; speedup vs baseline: 1.1928x; 1.0205x over previous
//
#include <hip/hip_runtime.h>
#include <math.h>

#define BATCH 8
#define CDIM 256
#define NDIM 2048
#define SCALE 0.0625f  // 1/sqrt(256)

typedef _Float16 half8v __attribute__((ext_vector_type(8)));
typedef _Float16 half4v __attribute__((ext_vector_type(4)));
typedef float floatx4 __attribute__((ext_vector_type(4)));

// workspace offsets (bytes)
#define WS_SPART 0                      // 8*16*2048 floats = 1 MB
#define WS_KT    1048576                // 8.4 MB
#define WS_QT    9437184                // 8.4 MB
#define WS_VT    17825792               // 8.4 MB (fp16 V, plain [b][c][i])
#define WS_EHT   26214400               // 67 MB
// total ws use: ~89 MB

// Bs/As chunk swizzle: per-row rotation, conflict-free for staging-store,
// MFMA fragment reads, and the W transpose gather.
#define BSWZ(c, j) (((((c) + (j) + ((j) >> 3)) & 7)) << 3)

// ---------------------------------------------------------------------------
// prep: K,Q -> fp16 transposed+tiled [b][ib(16)][cb(8)][i(128)][c(32)];
// V -> fp16 cast, layout unchanged [b][c][i].
// ---------------------------------------------------------------------------
__global__ __launch_bounds__(256) void prep_kernel(const float* __restrict__ Q,
                                                   const float* __restrict__ K,
                                                   const float* __restrict__ V,
                                                   _Float16* __restrict__ Kt,
                                                   _Float16* __restrict__ Qt,
                                                   _Float16* __restrict__ Vt) {
    if (blockIdx.y == 2) {
        const int t = threadIdx.x;
#pragma unroll
        for (int u = 0; u < 4; ++u) {
            const size_t idx = (size_t)blockIdx.x * 4096 + (u * 256 + t) * 4;
            float4 f = *(const float4*)&V[idx];
            half4v h = {(_Float16)f.x, (_Float16)f.y, (_Float16)f.z, (_Float16)f.w};
            *(half4v*)&Vt[idx] = h;
        }
        return;
    }
    const int g = blockIdx.x * 256 + threadIdx.x;
    const float* src = (blockIdx.y == 0) ? K : Q;
    _Float16* dst = (blockIdx.y == 0) ? Kt : Qt;
    const int b = g >> 15, r = g & 32767;
    const int iq = r & 511, cq = r >> 9;  // i-quad (512), c-quad (64)
    const float* p = src + (size_t)b * CDIM * NDIM + (size_t)(cq * 4) * NDIM + iq * 4;
    float fr[4][4];
    *(float4*)fr[0] = *(const float4*)(p);
    *(float4*)fr[1] = *(const float4*)(p + NDIM);
    *(float4*)fr[2] = *(const float4*)(p + 2 * NDIM);
    *(float4*)fr[3] = *(const float4*)(p + 3 * NDIM);
    const int cb = cq >> 3, cc0 = (cq & 7) * 4;
#pragma unroll
    for (int ii = 0; ii < 4; ++ii) {
        const int i = iq * 4 + ii;
        const int ib = i >> 7, il = i & 127;
        half4v h = {(_Float16)fr[0][ii], (_Float16)fr[1][ii],
                    (_Float16)fr[2][ii], (_Float16)fr[3][ii]};
        *(half4v*)&dst[((((size_t)(b * 16 + ib) * 8 + cb) * 128 + il) * 32) + cc0] = h;
    }
}

// ---------------------------------------------------------------------------
// GEMM1: E = exp(SCALE * K^T Q). NEW schedule: LDS double-buffer, ONE
// syncthreads per K-step, register prefetch 2 steps ahead. Dataflow,
// swizzles, epilogue identical to the proven round-2 version.
// ---------------------------------------------------------------------------
#define G1_LOAD(CB, A0, A1, B0, B1)                          \
    do {                                                     \
        A0 = *(const half8v*)(Ab + (CB) * 4096 + ci0 * 8);   \
        A1 = *(const half8v*)(Ab + (CB) * 4096 + ci1 * 8);   \
        B0 = *(const half8v*)(Bb + (CB) * 4096 + ci0 * 8);   \
        B1 = *(const half8v*)(Bb + (CB) * 4096 + ci1 * 8);   \
    } while (0)

#define G1_STAGE(ALp, BLp, A0, A1, B0, B1)    \
    do {                                      \
        *(half8v*)&(ALp)[oA0] = A0;           \
        *(half8v*)&(ALp)[oA1] = A1;           \
        *(half8v*)&(BLp)[oA0] = B0;           \
        *(half8v*)&(BLp)[oA1] = B1;           \
    } while (0)

#define G1_MFMA(ALp, BLp)                                                          \
    do {                                                                           \
        half8v af[4], bf[4];                                                       \
        _Pragma("unroll") for (int m = 0; m < 4; ++m)                              \
            af[m] = *(const half8v*)&(ALp)[(wy * 64 + m * 16 + lr) * 40 + quad * 8]; \
        _Pragma("unroll") for (int n = 0; n < 4; ++n)                              \
            bf[n] = *(const half8v*)&(BLp)[(wx * 64 + n * 16 + lr) * 40 + quad * 8]; \
        _Pragma("unroll") for (int m = 0; m < 4; ++m)                              \
            _Pragma("unroll") for (int n = 0; n < 4; ++n)                          \
                acc[m][n] = __builtin_amdgcn_mfma_f32_16x16x32_f16(                \
                    af[m], bf[n], acc[m][n], 0, 0, 0);                             \
    } while (0)

__global__ __launch_bounds__(256) void gemm1_kernel(const _Float16* __restrict__ Kt,
                                                    const _Float16* __restrict__ Qt,
                                                    _Float16* __restrict__ EhT,
                                                    float* __restrict__ Spart) {
    __shared__ _Float16 Al[2][128 * 40];
    __shared__ _Float16 Bl[2][128 * 40];
    __shared__ _Float16 LT[128 * 128];
    __shared__ float Sl[2][128];
    const int b = blockIdx.z, ib2 = blockIdx.y, jb2 = blockIdx.x;
    const _Float16* Ab = Kt + (size_t)(b * 16 + ib2) * 8 * 4096;
    const _Float16* Bb = Qt + (size_t)(b * 16 + jb2) * 8 * 4096;
    const int t = threadIdx.x, wave = t >> 6, lane = t & 63;
    const int wy = wave >> 1, wx = wave & 1, quad = lane >> 4, lr = lane & 15;
    floatx4 acc[4][4] = {};
    const int ci0 = t * 2, ci1 = t * 2 + 1;
    const int oA0 = (ci0 >> 2) * 40 + (ci0 & 3) * 8;
    const int oA1 = (ci1 >> 2) * 40 + (ci1 & 3) * 8;

    half8v a00, a01, b00, b01, a10, a11, b10, b11;
    G1_LOAD(0, a00, a01, b00, b01);
    G1_STAGE(Al[0], Bl[0], a00, a01, b00, b01);
    G1_LOAD(1, a10, a11, b10, b11);
    __syncthreads();
#pragma unroll
    for (int cbp = 0; cbp < 4; ++cbp) {
        const int cbE = cbp * 2, cbO = cbp * 2 + 1;
        // even step: buf0 current, regs set1 hold tile cbE+1
        G1_STAGE(Al[1], Bl[1], a10, a11, b10, b11);
        G1_LOAD((cbE + 2) & 7, a00, a01, b00, b01);
        G1_MFMA(Al[0], Bl[0]);
        __syncthreads();
        // odd step: buf1 current, regs set0 hold tile cbO+1
        G1_STAGE(Al[0], Bl[0], a00, a01, b00, b01);
        G1_LOAD((cbO + 2) & 7, a10, a11, b10, b11);
        G1_MFMA(Al[1], Bl[1]);
        __syncthreads();
    }

    // epilogue: exp -> LDS transpose (chunk-swizzled) + column partial sums
    float psum[4] = {0.f, 0.f, 0.f, 0.f};
#pragma unroll
    for (int m = 0; m < 4; ++m) {
#pragma unroll
        for (int n = 0; n < 4; ++n) {
            const int j_loc = wx * 64 + n * 16 + lr;
#pragma unroll
            for (int r = 0; r < 4; ++r) {
                const int i_loc = wy * 64 + m * 16 + quad * 4 + r;
                float e = __expf(acc[m][n][r] * SCALE);
                psum[n] += e;
                LT[j_loc * 128 + (((i_loc >> 3) ^ (j_loc & 7)) << 3) + (i_loc & 7)] = (_Float16)e;
            }
        }
    }
#pragma unroll
    for (int n = 0; n < 4; ++n) {
        float s = psum[n];
        s += __shfl_xor(s, 16, 64);
        s += __shfl_xor(s, 32, 64);
        if (quad == 0) Sl[wy][wx * 64 + n * 16 + lr] = s;
    }
    __syncthreads();
    if (t < 128)
        Spart[((size_t)(b * 16 + ib2)) * 2048 + jb2 * 128 + t] = Sl[0][t] + Sl[1][t];

    const int jh = wave >> 1, ih = wave & 1;
    _Float16* dst = EhT + ((size_t)((b * 32 + jb2 * 2 + jh) * 32) + ib2 * 2 + ih) * 4096;
#pragma unroll
    for (int cc = 0; cc < 8; ++cc) {
        const int j = jh * 64 + cc * 8 + (lane >> 3);
        half8v h = *(const half8v*)&LT[j * 128 + (((ih * 8 + (lane & 7)) ^ (lane >> 3)) << 3)];
        *(half8v*)&dst[cc * 512 + lane * 8] = h;
    }
}

// ---------------------------------------------------------------------------
// GEMM2 (fused): out[b,c,j] = invS[j] * sum_i V[c,i] * E[i,j]  AND
// W[b,i,j] = E[i,j] * invS[j]. Block 128c x 128j, 512 threads (8 waves),
// grid 16x2x8. NEW schedule: LDS double-buffer, ONE syncthreads per
// K-step, register prefetch 2 steps ahead. Dataflow/swizzles unchanged.
// ---------------------------------------------------------------------------
#define G2_LOAD(IT, AV, BV)                                                        \
    do {                                                                           \
        _Pragma("unroll") for (int u = 0; u < 2; ++u) {                            \
            const int f = u * 512 + t;                                             \
            const int c = f >> 3, i8 = f & 7;                                      \
            AV[u] = *(const half8v*)&Vtb[(size_t)c * 2048 + (IT) * 64 + i8 * 8];   \
        }                                                                          \
        _Pragma("unroll") for (int u = 0; u < 2; ++u) {                            \
            const int f = u * 512 + t;                                             \
            const int jl = f >> 3, c8 = f & 7;                                     \
            const int jbv = jb2 * 2 + (jl >> 6);                                   \
            BV[u] = *(const half8v*)&EhT[((size_t)((b * 32 + jbv) * 32) + (IT)) *  \
                                             4096 +                                \
                                         (jl & 63) * 64 + c8 * 8];                 \
        }                                                                          \
    } while (0)

#define G2_STAGE(ASp, BSp, AV, BV)                                \
    do {                                                          \
        _Pragma("unroll") for (int u = 0; u < 2; ++u) {           \
            const int f = u * 512 + t;                            \
            const int c = f >> 3, i8 = f & 7;                     \
            *(half8v*)&(ASp)[c * 72 + BSWZ(i8, c)] = AV[u];       \
        }                                                         \
        _Pragma("unroll") for (int u = 0; u < 2; ++u) {           \
            const int f = u * 512 + t;                            \
            const int jl = f >> 3, c8 = f & 7;                    \
            *(half8v*)&(BSp)[jl * 72 + BSWZ(c8, jl)] = BV[u];     \
        }                                                         \
    } while (0)

#define G2_MFMA(ASp, BSp)                                                          \
    do {                                                                           \
        _Pragma("unroll") for (int ks = 0; ks < 2; ++ks) {                         \
            half8v af[4], bf[2];                                                   \
            _Pragma("unroll") for (int m = 0; m < 4; ++m) {                        \
                const int row = wy * 64 + m * 16 + lr;                             \
                af[m] = *(const half8v*)&(ASp)[row * 72 + BSWZ(ks * 4 + quad, row)]; \
            }                                                                      \
            _Pragma("unroll") for (int n = 0; n < 2; ++n) {                        \
                const int row = wx * 32 + n * 16 + lr;                             \
                bf[n] = *(const half8v*)&(BSp)[row * 72 + BSWZ(ks * 4 + quad, row)]; \
            }                                                                      \
            _Pragma("unroll") for (int m = 0; m < 4; ++m)                          \
                _Pragma("unroll") for (int n = 0; n < 2; ++n)                      \
                    acc[m][n] = __builtin_amdgcn_mfma_f32_16x16x32_f16(            \
                        af[m], bf[n], acc[m][n], 0, 0, 0);                         \
        }                                                                          \
    } while (0)

#define G2_WDUTY(BSp, IT)                                                          \
    do {                                                                           \
        half8v hv0 = *(const half8v*)&(BSp)[j0 * 72 + BSWZ(ti, j0)];               \
        half8v hv1 = *(const half8v*)&(BSp)[(j0 + 1) * 72 + BSWZ(ti, j0 + 1)];     \
        float* Wr = Wb + (size_t)((IT) * 64 + ti * 8) * 2048;                      \
        _Pragma("unroll") for (int e = 0; e < 8; ++e) {                            \
            float2 o = make_float2((float)hv0[e] * iv0, (float)hv1[e] * iv1);      \
            *(float2*)&Wr[(size_t)e * 2048 + j0] = o;                              \
        }                                                                          \
    } while (0)

__global__ __launch_bounds__(512) void gemm2_kernel(const _Float16* __restrict__ Vt,
                                                    const _Float16* __restrict__ EhT,
                                                    const float* __restrict__ Spart,
                                                    float* __restrict__ W,
                                                    float* __restrict__ Out) {
    __shared__ _Float16 As[2][128 * 72];
    __shared__ _Float16 Bs[2][128 * 72];
    __shared__ float invSl[128];
    const int b = blockIdx.z, cc2 = blockIdx.y, jb2 = blockIdx.x;
    const int t = threadIdx.x, wave = t >> 6, lane = t & 63;
    const int wy = wave >> 2, wx = wave & 3, quad = lane >> 4, lr = lane & 15;
    const _Float16* Vtb = Vt + ((size_t)(b * 256 + cc2 * 128)) * 2048;
    floatx4 acc[4][2] = {};

    if (t < 128) {
        float s = 0.f;
#pragma unroll
        for (int p = 0; p < 16; ++p)
            s += Spart[((size_t)(b * 16 + p)) * 2048 + jb2 * 128 + t];
        invSl[t] = 1.0f / s;
    }

    // W-path thread mapping: 2 consecutive j x 8 consecutive i per thread
    const int j0 = (t & 63) * 2, ti = t >> 6;
    float* Wb = W + ((size_t)b * 2048) * 2048 + jb2 * 128;
    const bool dutyE = (cc2 == 0), dutyO = (cc2 == 1);

    half8v av0[2], bv0[2], av1[2], bv1[2];
    G2_LOAD(0, av0, bv0);
    G2_STAGE(As[0], Bs[0], av0, bv0);
    G2_LOAD(1, av1, bv1);
    __syncthreads();
    const float iv0 = invSl[j0], iv1 = invSl[j0 + 1];

    for (int ip = 0; ip < 16; ++ip) {
        const int itE = ip * 2, itO = ip * 2 + 1;
        // even step: buf0 current, regs set1 hold tile itE+1
        G2_STAGE(As[1], Bs[1], av1, bv1);
        G2_LOAD((itE + 2) & 31, av0, bv0);
        G2_MFMA(As[0], Bs[0]);
        if (dutyE) G2_WDUTY(Bs[0], itE);
        __syncthreads();
        // odd step: buf1 current, regs set0 hold tile itO+1
        G2_STAGE(As[0], Bs[0], av0, bv0);
        G2_LOAD((itO + 2) & 31, av1, bv1);
        G2_MFMA(As[1], Bs[1]);
        if (dutyO) G2_WDUTY(Bs[1], itO);
        __syncthreads();
    }

    float* Ob = Out + ((size_t)(b * 256 + cc2 * 128)) * 2048 + jb2 * 128;
    float iv[2];
#pragma unroll
    for (int n = 0; n < 2; ++n)
        iv[n] = invSl[wx * 32 + n * 16 + lr];
#pragma unroll
    for (int m = 0; m < 4; ++m) {
        const int c0r = wy * 64 + m * 16 + quad * 4;
#pragma unroll
        for (int n = 0; n < 2; ++n) {
            const int j = wx * 32 + n * 16 + lr;
#pragma unroll
            for (int r = 0; r < 4; ++r)
                Ob[(size_t)(c0r + r) * 2048 + j] = acc[m][n][r] * iv[n];
        }
    }
}

extern "C" void kernel_launch(void* const* d_in, const int* in_sizes, int n_in,
                              void* d_out, int out_size, void* d_ws, size_t ws_size,
                              hipStream_t stream) {
    const float* q = (const float*)d_in[0];
    const float* k = (const float*)d_in[1];
    const float* v = (const float*)d_in[2];
    float* out = (float*)d_out;
    float* w = out + (size_t)BATCH * CDIM * NDIM;  // weights region

    char* ws = (char*)d_ws;
    float* Spart = (float*)(ws + WS_SPART);
    _Float16* Kt = (_Float16*)(ws + WS_KT);
    _Float16* Qt = (_Float16*)(ws + WS_QT);
    _Float16* Vt = (_Float16*)(ws + WS_VT);
    _Float16* EhT = (_Float16*)(ws + WS_EHT);

    prep_kernel<<<dim3(1024, 3), 256, 0, stream>>>(q, k, v, Kt, Qt, Vt);
    gemm1_kernel<<<dim3(16, 16, 8), 256, 0, stream>>>(Kt, Qt, EhT, Spart);
    gemm2_kernel<<<dim3(16, 2, 8), 512, 0, stream>>>(Vt, EhT, Spart, w, out);
}